// Round 1
// baseline (719.663 us; speedup 1.0000x reference)
//
#include <hip/hip_runtime.h>

#define NN 50000
#define NE 800000

typedef float f32x4 __attribute__((ext_vector_type(4)));
typedef short s16x8 __attribute__((ext_vector_type(8)));
typedef unsigned short u16;

__device__ __forceinline__ u16 f2bf(float f) {
  union { float f; unsigned u; } v; v.f = f;
  unsigned r = v.u + 0x7FFFu + ((v.u >> 16) & 1u);
  return (u16)(r >> 16);
}

__device__ __forceinline__ void st_bf4(u16* p, f32x4 v) {
  ushort4 pv;
  pv.x = f2bf(v.x); pv.y = f2bf(v.y); pv.z = f2bf(v.z); pv.w = f2bf(v.w);
  *(ushort4*)p = pv;
}

__global__ void zero_kernel(f32x4* __restrict__ p) {
  f32x4 z; z[0] = 0.f; z[1] = 0.f; z[2] = 0.f; z[3] = 0.f;
  p[(size_t)blockIdx.x * 256 + threadIdx.x] = z;
}

// pack W[K x N] fp32 -> bf16, fragment-major for 16x16x32 MFMA B-operand:
// out[((ks*NT+nt)*64 + lane)*8 + j] = W[ks*32 + (lane>>4)*8 + j][nt*16 + (lane&15)]
__device__ __forceinline__ void pack_one(const float* __restrict__ W, int N,
                                         u16* __restrict__ out, int t) {
  int j = t & 7, lane = (t >> 3) & 63, f = t >> 9;
  int NT = N >> 4;
  int nt = f % NT, ks = f / NT;
  int row = ks * 32 + ((lane >> 4) << 3) + j;
  int col = nt * 16 + (lane & 15);
  out[t] = f2bf(W[row * N + col]);
}

__global__ void pack_kernel(const float* __restrict__ We1, const float* __restrict__ We2,
                            const float* __restrict__ Wa1, const float* __restrict__ Wa2,
                            const float* __restrict__ Wn1, const float* __restrict__ Wn2,
                            u16* __restrict__ out) {
  int t = blockIdx.x * 256 + threadIdx.x;
  if (t < 24576)      pack_one(We1, 128, out,          t);
  else if (t < 32768) pack_one(We2, 64,  out + 24576,  t - 24576);
  else if (t < 57344) pack_one(Wa1, 128, out + 32768,  t - 32768);
  else if (t < 65536) pack_one(Wa2, 64,  out + 57344,  t - 57344);
  else if (t < 81920) pack_one(Wn1, 128, out + 65536,  t - 65536);
  else if (t < 90112) pack_one(Wn2, 64,  out + 81920,  t - 81920);
}

__global__ __launch_bounds__(256, 2)
void edge_kernel(const float* __restrict__ nf, const float* __restrict__ ef,
                 const int* __restrict__ src, const int* __restrict__ dst,
                 const u16* __restrict__ W1e, const float* __restrict__ b1e,
                 const u16* __restrict__ W2e, const float* __restrict__ b2e,
                 const u16* __restrict__ W1a, const float* __restrict__ b1a,
                 const u16* __restrict__ W2a, const float* __restrict__ b2a,
                 float* __restrict__ out_ef, float* __restrict__ agg) {
  __shared__ u16 xe[4][16 * 200];   // 16 edges x 192 feats (+8 pad), bf16
  __shared__ u16 hs[4][16 * 136];   // 16 x 128 hidden (+8 pad), bf16
  __shared__ int sdst[4][16];
  const int w = threadIdx.x >> 6, lane = threadIdx.x & 63;
  const int e0 = blockIdx.x * 64 + w * 16;
  const int er = lane >> 4, c4 = (lane & 15) * 4;

  // ---- stage x_e = [nf[src] | nf[dst] | ef] into LDS as bf16 ----
  #pragma unroll
  for (int g = 0; g < 4; ++g) {
    int el = g * 4 + er;
    int e = e0 + el;
    int s = src[e], d = dst[e];
    if (c4 == 0) sdst[w][el] = d;
    f32x4 fs = *(const f32x4*)(nf + (size_t)s * 64 + c4);
    f32x4 fd = *(const f32x4*)(nf + (size_t)d * 64 + c4);
    f32x4 fe = *(const f32x4*)(ef + (size_t)e * 64 + c4);
    u16* row = &xe[w][el * 200];
    st_bf4(row + c4, fs);
    st_bf4(row + 64 + c4, fd);
    st_bf4(row + 128 + c4, fe);
  }
  __syncthreads();

  const int m = lane & 15, q = lane >> 4;
  // A fragments of x_e tile [16 x 192]
  s16x8 a1[6];
  #pragma unroll
  for (int k = 0; k < 6; ++k)
    a1[k] = *(const s16x8*)&xe[w][m * 200 + k * 32 + q * 8];

  // ---- e-MLP layer 1: [16x192] @ [192x128] ----
  f32x4 acc[8];
  #pragma unroll
  for (int i = 0; i < 8; ++i) { acc[i][0] = 0.f; acc[i][1] = 0.f; acc[i][2] = 0.f; acc[i][3] = 0.f; }
  #pragma unroll
  for (int nt = 0; nt < 8; ++nt)
    #pragma unroll
    for (int k = 0; k < 6; ++k) {
      s16x8 b = *(const s16x8*)(W1e + ((size_t)(k * 8 + nt) * 64 + lane) * 8);
      acc[nt] = __builtin_amdgcn_mfma_f32_16x16x32_bf16(a1[k], b, acc[nt], 0, 0, 0);
    }
  #pragma unroll
  for (int nt = 0; nt < 8; ++nt) {
    float bv = b1e[nt * 16 + m];
    #pragma unroll
    for (int r = 0; r < 4; ++r) {
      float h = acc[nt][r] + bv;
      h = h > 0.f ? h : 0.f;
      hs[w][(q * 4 + r) * 136 + nt * 16 + m] = f2bf(h);
    }
  }
  __syncthreads();

  // ---- e-MLP layer 2: [16x128] @ [128x64] ----
  s16x8 a2[4];
  #pragma unroll
  for (int k = 0; k < 4; ++k)
    a2[k] = *(const s16x8*)&hs[w][m * 136 + k * 32 + q * 8];
  f32x4 eo[4];
  #pragma unroll
  for (int i = 0; i < 4; ++i) { eo[i][0] = 0.f; eo[i][1] = 0.f; eo[i][2] = 0.f; eo[i][3] = 0.f; }
  #pragma unroll
  for (int nt = 0; nt < 4; ++nt)
    #pragma unroll
    for (int k = 0; k < 4; ++k) {
      s16x8 b = *(const s16x8*)(W2e + ((size_t)(k * 4 + nt) * 64 + lane) * 8);
      eo[nt] = __builtin_amdgcn_mfma_f32_16x16x32_bf16(a2[k], b, eo[nt], 0, 0, 0);
    }

  // ---- gate-MLP layer 1 (reuses a1) ----
  f32x4 accg[8];
  #pragma unroll
  for (int i = 0; i < 8; ++i) { accg[i][0] = 0.f; accg[i][1] = 0.f; accg[i][2] = 0.f; accg[i][3] = 0.f; }
  #pragma unroll
  for (int nt = 0; nt < 8; ++nt)
    #pragma unroll
    for (int k = 0; k < 6; ++k) {
      s16x8 b = *(const s16x8*)(W1a + ((size_t)(k * 8 + nt) * 64 + lane) * 8);
      accg[nt] = __builtin_amdgcn_mfma_f32_16x16x32_bf16(a1[k], b, accg[nt], 0, 0, 0);
    }
  __syncthreads();   // a2 reads done before hs overwrite
  #pragma unroll
  for (int nt = 0; nt < 8; ++nt) {
    float bv = b1a[nt * 16 + m];
    #pragma unroll
    for (int r = 0; r < 4; ++r) {
      float h = accg[nt][r] + bv;
      h = h > 0.f ? h : 0.f;
      hs[w][(q * 4 + r) * 136 + nt * 16 + m] = f2bf(h);
    }
  }
  __syncthreads();

  // ---- gate-MLP layer 2 ----
  s16x8 a2g[4];
  #pragma unroll
  for (int k = 0; k < 4; ++k)
    a2g[k] = *(const s16x8*)&hs[w][m * 136 + k * 32 + q * 8];
  f32x4 go[4];
  #pragma unroll
  for (int i = 0; i < 4; ++i) { go[i][0] = 0.f; go[i][1] = 0.f; go[i][2] = 0.f; go[i][3] = 0.f; }
  #pragma unroll
  for (int nt = 0; nt < 4; ++nt)
    #pragma unroll
    for (int k = 0; k < 4; ++k) {
      s16x8 b = *(const s16x8*)(W2a + ((size_t)(k * 4 + nt) * 64 + lane) * 8);
      go[nt] = __builtin_amdgcn_mfma_f32_16x16x32_bf16(a2g[k], b, go[nt], 0, 0, 0);
    }

  // ---- epilogue: updated_ef = sigmoid(gate) * e_out; scatter-add to agg ----
  #pragma unroll
  for (int nt = 0; nt < 4; ++nt) {
    int col = nt * 16 + m;
    float be2v = b2e[col], ba2v = b2a[col];
    #pragma unroll
    for (int r = 0; r < 4; ++r) {
      int rowi = q * 4 + r;
      int e = e0 + rowi;
      float ev = eo[nt][r] + be2v;
      float gv = go[nt][r] + ba2v;
      float gs = 1.f / (1.f + __expf(-gv));
      float val = gs * ev;
      out_ef[(size_t)e * 64 + col] = val;
      atomicAdd(agg + (size_t)sdst[w][rowi] * 64 + col, val);
    }
  }
}

__global__ __launch_bounds__(256, 2)
void node_kernel(const float* __restrict__ nf, const float* __restrict__ agg,
                 const u16* __restrict__ W1n, const float* __restrict__ b1n,
                 const u16* __restrict__ W2n, const float* __restrict__ b2n,
                 float* __restrict__ out_nf) {
  __shared__ u16 xn[4][16 * 136];
  __shared__ u16 hn[4][16 * 136];
  const int w = threadIdx.x >> 6, lane = threadIdx.x & 63;
  const int n0 = blockIdx.x * 64 + w * 16;
  const int er = lane >> 4, c4 = (lane & 15) * 4;

  #pragma unroll
  for (int g = 0; g < 4; ++g) {
    int nl = g * 4 + er;
    int n = n0 + nl; if (n >= NN) n = NN - 1;
    f32x4 fa = *(const f32x4*)(agg + (size_t)n * 64 + c4);
    f32x4 fn = *(const f32x4*)(nf + (size_t)n * 64 + c4);
    u16* row = &xn[w][nl * 136];
    st_bf4(row + c4, fa);
    st_bf4(row + 64 + c4, fn);
  }
  __syncthreads();

  const int m = lane & 15, q = lane >> 4;
  s16x8 a1[4];
  #pragma unroll
  for (int k = 0; k < 4; ++k)
    a1[k] = *(const s16x8*)&xn[w][m * 136 + k * 32 + q * 8];
  f32x4 acc[8];
  #pragma unroll
  for (int i = 0; i < 8; ++i) { acc[i][0] = 0.f; acc[i][1] = 0.f; acc[i][2] = 0.f; acc[i][3] = 0.f; }
  #pragma unroll
  for (int nt = 0; nt < 8; ++nt)
    #pragma unroll
    for (int k = 0; k < 4; ++k) {
      s16x8 b = *(const s16x8*)(W1n + ((size_t)(k * 8 + nt) * 64 + lane) * 8);
      acc[nt] = __builtin_amdgcn_mfma_f32_16x16x32_bf16(a1[k], b, acc[nt], 0, 0, 0);
    }
  #pragma unroll
  for (int nt = 0; nt < 8; ++nt) {
    float bv = b1n[nt * 16 + m];
    #pragma unroll
    for (int r = 0; r < 4; ++r) {
      float h = acc[nt][r] + bv;
      h = h > 0.f ? h : 0.f;
      hn[w][(q * 4 + r) * 136 + nt * 16 + m] = f2bf(h);
    }
  }
  __syncthreads();

  s16x8 a2[4];
  #pragma unroll
  for (int k = 0; k < 4; ++k)
    a2[k] = *(const s16x8*)&hn[w][m * 136 + k * 32 + q * 8];
  f32x4 o[4];
  #pragma unroll
  for (int i = 0; i < 4; ++i) { o[i][0] = 0.f; o[i][1] = 0.f; o[i][2] = 0.f; o[i][3] = 0.f; }
  #pragma unroll
  for (int nt = 0; nt < 4; ++nt)
    #pragma unroll
    for (int k = 0; k < 4; ++k) {
      s16x8 b = *(const s16x8*)(W2n + ((size_t)(k * 4 + nt) * 64 + lane) * 8);
      o[nt] = __builtin_amdgcn_mfma_f32_16x16x32_bf16(a2[k], b, o[nt], 0, 0, 0);
    }
  #pragma unroll
  for (int nt = 0; nt < 4; ++nt) {
    int col = nt * 16 + m;
    float bv = b2n[col];
    #pragma unroll
    for (int r = 0; r < 4; ++r) {
      int rowi = q * 4 + r;
      int n = n0 + rowi;
      if (n < NN) out_nf[(size_t)n * 64 + col] = o[nt][r] + bv;
    }
  }
}

extern "C" void kernel_launch(void* const* d_in, const int* in_sizes, int n_in,
                              void* d_out, int out_size, void* d_ws, size_t ws_size,
                              hipStream_t stream) {
  const float* nf  = (const float*)d_in[0];
  const float* ef  = (const float*)d_in[1];
  const int*   src = (const int*)d_in[2];
  const int*   dst = (const int*)d_in[3];
  const float* We1 = (const float*)d_in[4];
  const float* be1 = (const float*)d_in[5];
  const float* We2 = (const float*)d_in[6];
  const float* be2 = (const float*)d_in[7];
  const float* Wa1 = (const float*)d_in[8];
  const float* ba1 = (const float*)d_in[9];
  const float* Wa2 = (const float*)d_in[10];
  const float* ba2 = (const float*)d_in[11];
  const float* Wn1 = (const float*)d_in[12];
  const float* bn1 = (const float*)d_in[13];
  const float* Wn2 = (const float*)d_in[14];
  const float* bn2 = (const float*)d_in[15];
  float* out = (float*)d_out;
  float* agg = (float*)d_ws;                                   // NN*64 fp32 = 12.8 MB
  u16* pk = (u16*)((char*)d_ws + (size_t)NN * 64 * 4);         // packed bf16 weights

  zero_kernel<<<3125, 256, 0, stream>>>((f32x4*)agg);          // 3.2M floats
  pack_kernel<<<352, 256, 0, stream>>>(We1, We2, Wa1, Wa2, Wn1, Wn2, pk);
  edge_kernel<<<NE / 64, 256, 0, stream>>>(nf, ef, src, dst,
      pk, be1, pk + 24576, be2, pk + 32768, ba1, pk + 57344, ba2,
      out + (size_t)NN * 64, agg);
  node_kernel<<<(NN + 63) / 64, 256, 0, stream>>>(nf, agg,
      pk + 65536, bn1, pk + 81920, bn2, out);
}